// Round 1
// baseline (4204.748 us; speedup 1.0000x reference)
//
#include <hip/hip_runtime.h>
#include <math.h>

#define B_ 128
#define V_ 32
#define D_ 64
#define H_ 256
#define E_ 992
#define ME (B_*E_)   // 126976
#define MV (B_*V_)   // 4096

__device__ __forceinline__ float sigf(float x) {
    x = fminf(fmaxf(x, -30.f), 30.f);
    return 1.f / (1.f + __expf(-x));
}
__device__ __forceinline__ float tanhf_fast(float x) {
    x = fminf(fmaxf(x, -15.f), 15.f);
    float e = __expf(2.f * x);
    return (e - 1.f) / (e + 1.f);
}

// ---------------------------------------------------------------------------
// Generic tiled GEMM: out[m,n] = act( sum_k A[m,k] * W[n*ldw+k] + bias[n]
//                                     [+ ES[b,send,n] + ER[b,recv,n]] )
// A: [M,K] row-major (lda), W: [N,K] row-major (ldw), out: [M,N] contiguous.
// EPI==1: add edge-gathered node terms (used for MLP4 layer 1).
// Tiles: 64x64 output per block, K-step 32, 256 threads, 4x4 microtile.
// ---------------------------------------------------------------------------
template<int EPI>
__global__ __launch_bounds__(256)
void gemm_k(const float* __restrict__ A, int lda,
            const float* __restrict__ W, int ldw,
            const float* __restrict__ bias,
            float* __restrict__ out,
            int M, int N, int K, int do_relu,
            const float* __restrict__ ES, const float* __restrict__ ER)
{
    __shared__ float As[32][68];   // [k][m], +4 pad: conflict-free, 16B-aligned rows
    __shared__ float Ws[32][68];   // [k][n]
    const int m0 = blockIdx.x * 64;
    const int n0 = blockIdx.y * 64;
    const int t  = threadIdx.x;
    const int tx = t & 15, ty = t >> 4;
    const int lm = t >> 3;          // 0..31
    const int lk = (t & 7) * 4;     // 0,4,...,28

    float acc[4][4] = {};

    for (int k0 = 0; k0 < K; k0 += 32) {
        #pragma unroll
        for (int h = 0; h < 2; ++h) {
            const int m = m0 + lm + h * 32;
            const float4 v = *(const float4*)(A + (size_t)m * lda + k0 + lk);
            As[lk + 0][lm + h * 32] = v.x;
            As[lk + 1][lm + h * 32] = v.y;
            As[lk + 2][lm + h * 32] = v.z;
            As[lk + 3][lm + h * 32] = v.w;
            const int n = n0 + lm + h * 32;
            const float4 w = *(const float4*)(W + (size_t)n * ldw + k0 + lk);
            Ws[lk + 0][lm + h * 32] = w.x;
            Ws[lk + 1][lm + h * 32] = w.y;
            Ws[lk + 2][lm + h * 32] = w.z;
            Ws[lk + 3][lm + h * 32] = w.w;
        }
        __syncthreads();
        #pragma unroll
        for (int kk = 0; kk < 32; ++kk) {
            float a[4], b[4];
            #pragma unroll
            for (int i = 0; i < 4; ++i) a[i] = As[kk][ty * 4 + i];
            #pragma unroll
            for (int j = 0; j < 4; ++j) b[j] = Ws[kk][tx * 4 + j];
            #pragma unroll
            for (int i = 0; i < 4; ++i)
                #pragma unroll
                for (int j = 0; j < 4; ++j)
                    acc[i][j] = fmaf(a[i], b[j], acc[i][j]);
        }
        __syncthreads();
    }

    #pragma unroll
    for (int i = 0; i < 4; ++i) {
        const int m = m0 + ty * 4 + i;
        const size_t ob = (size_t)m * N;
        size_t bs = 0, br = 0;
        if (EPI == 1) {
            const int bb = m / E_;
            const int e  = m - bb * E_;
            const int s  = e / 31;
            const int jj = e - s * 31;
            const int r  = jj + (jj >= s ? 1 : 0);
            bs = ((size_t)bb * V_ + s) * H_;
            br = ((size_t)bb * V_ + r) * H_;
        }
        #pragma unroll
        for (int j = 0; j < 4; ++j) {
            const int n = n0 + tx * 4 + j;
            float v = acc[i][j];
            if (EPI == 1) v += ES[bs + n] + ER[br + n];
            if (bias) v += bias[n];
            if (do_relu) v = fmaxf(v, 0.f);
            out[ob + n] = v;
        }
    }
}

// ---------------------------------------------------------------------------
// MLP2 layer 1: out[b,e,n] = relu(Ys[b,send(e),n] + Yr[b,recv(e),n] + bias[n])
// ---------------------------------------------------------------------------
__global__ __launch_bounds__(256)
void edge_l1_k(const float* __restrict__ Ys, const float* __restrict__ Yr,
               const float* __restrict__ bias, float* __restrict__ out)
{
    const size_t g = (size_t)blockIdx.x * 256 + threadIdx.x;  // over ME*H
    const int n   = (int)(g & 255);
    const int row = (int)(g >> 8);
    const int b   = row / E_;
    const int e   = row - b * E_;
    const int s   = e / 31;
    const int j   = e - s * 31;
    const int r   = j + (j >= s ? 1 : 0);
    float v = Ys[((size_t)b * V_ + s) * H_ + n]
            + Yr[((size_t)b * V_ + r) * H_ + n]
            + bias[n];
    out[g] = fmaxf(v, 0.f);
}

// ---------------------------------------------------------------------------
// edge->node aggregation: outv[b,v,h] = (1/31) * sum_{e: recv(e)==v} X2[b,e,h]
// ---------------------------------------------------------------------------
__global__ __launch_bounds__(256)
void agg_k(const float* __restrict__ X2, float* __restrict__ outv)
{
    const int g = blockIdx.x * 256 + threadIdx.x;  // over MV*H = 1M
    const int h = g & 255;
    const int v = (g >> 8) & 31;
    const int b = g >> 13;
    float s = 0.f;
    #pragma unroll
    for (int snd = 0; snd < 32; ++snd) {
        if (snd == v) continue;
        const int e = snd * 31 + v - (snd < v ? 1 : 0);
        s += X2[((size_t)b * E_ + e) * H_ + h];
    }
    outv[g] = s * (1.f / 31.f);
}

// ---------------------------------------------------------------------------
// Fused LSTM: gates = x4@wih.T + bih + h0@whh.T + bhh, then cell update.
// Block computes a 64-row x 32-j tile with ALL FOUR gates co-resident so the
// nonlinearity runs in the epilogue and h1/c1 go straight to d_out.
// Thread: 4 rows x 2 j x 4 gates = 32 accumulators.
// ---------------------------------------------------------------------------
__global__ __launch_bounds__(256)
void lstm_k(const float* __restrict__ x4, const float* __restrict__ h0,
            const float* __restrict__ c0,
            const float* __restrict__ wih, const float* __restrict__ whh,
            const float* __restrict__ bih, const float* __restrict__ bhh,
            float* __restrict__ h1, float* __restrict__ c1)
{
    __shared__ float As[32][68];    // [k][row]
    __shared__ float Ws[32][132];   // [k][gate*32+jj]
    const int m0 = blockIdx.x * 64;
    const int j0 = blockIdx.y * 32;
    const int t  = threadIdx.x;
    const int jg = t & 15, rg = t >> 4;
    const int lm = t >> 3, lk = (t & 7) * 4;

    float acc[4][2][4] = {};

    for (int ph = 0; ph < 2; ++ph) {
        const float* Ap = ph ? h0  : x4;
        const float* Wp = ph ? whh : wih;
        for (int k0 = 0; k0 < 256; k0 += 32) {
            #pragma unroll
            for (int h = 0; h < 2; ++h) {
                const int m = m0 + lm + h * 32;
                const float4 v = *(const float4*)(Ap + (size_t)m * 256 + k0 + lk);
                As[lk + 0][lm + h * 32] = v.x;
                As[lk + 1][lm + h * 32] = v.y;
                As[lk + 2][lm + h * 32] = v.z;
                As[lk + 3][lm + h * 32] = v.w;
            }
            #pragma unroll
            for (int p = 0; p < 4; ++p) {
                const int nl   = (t >> 3) + p * 32;     // 0..127
                const int gate = nl >> 5;
                const int jj   = nl & 31;
                const int ng   = gate * 256 + j0 + jj;
                const float4 w = *(const float4*)(Wp + (size_t)ng * 256 + k0 + lk);
                Ws[lk + 0][nl] = w.x;
                Ws[lk + 1][nl] = w.y;
                Ws[lk + 2][nl] = w.z;
                Ws[lk + 3][nl] = w.w;
            }
            __syncthreads();
            #pragma unroll
            for (int kk = 0; kk < 32; ++kk) {
                float a[4];
                #pragma unroll
                for (int i = 0; i < 4; ++i) a[i] = As[kk][rg * 4 + i];
                #pragma unroll
                for (int g = 0; g < 4; ++g) {
                    const float w0 = Ws[kk][g * 32 + jg * 2 + 0];
                    const float w1 = Ws[kk][g * 32 + jg * 2 + 1];
                    #pragma unroll
                    for (int i = 0; i < 4; ++i) {
                        acc[i][0][g] = fmaf(a[i], w0, acc[i][0][g]);
                        acc[i][1][g] = fmaf(a[i], w1, acc[i][1][g]);
                    }
                }
            }
            __syncthreads();
        }
    }

    #pragma unroll
    for (int i = 0; i < 4; ++i) {
        const int row = m0 + rg * 4 + i;
        #pragma unroll
        for (int u = 0; u < 2; ++u) {
            const int j = j0 + jg * 2 + u;
            const float gi = acc[i][u][0] + bih[j]       + bhh[j];
            const float gf = acc[i][u][1] + bih[256 + j] + bhh[256 + j];
            const float gg = acc[i][u][2] + bih[512 + j] + bhh[512 + j];
            const float go = acc[i][u][3] + bih[768 + j] + bhh[768 + j];
            const float cp = c0[(size_t)row * 256 + j];
            const float cn = sigf(gf) * cp + sigf(gi) * tanhf_fast(gg);
            const float hn = sigf(go) * tanhf_fast(cn);
            c1[(size_t)row * 256 + j] = cn;
            h1[(size_t)row * 256 + j] = hn;
        }
    }
}

// ---------------------------------------------------------------------------
// Prior layer 3: out[row, 0:2] = H @ pw3.T + pb3  (N=2, K=256)
// 16 threads per row, shuffle-reduce within 16-lane groups.
// ---------------------------------------------------------------------------
__global__ __launch_bounds__(256)
void prior3_k(const float* __restrict__ Hin, const float* __restrict__ w,
              const float* __restrict__ bias, float* __restrict__ out)
{
    const int t   = threadIdx.x;
    const int row = blockIdx.x * 16 + (t >> 4);
    const int kb  = (t & 15) * 16;
    const float* a = Hin + (size_t)row * 256 + kb;
    float p0 = 0.f, p1 = 0.f;
    #pragma unroll
    for (int u = 0; u < 4; ++u) {
        const float4 av = *(const float4*)(a + u * 4);
        const float4 w0 = *(const float4*)(w + kb + u * 4);
        const float4 w1 = *(const float4*)(w + 256 + kb + u * 4);
        p0 += av.x * w0.x + av.y * w0.y + av.z * w0.z + av.w * w0.w;
        p1 += av.x * w1.x + av.y * w1.y + av.z * w1.z + av.w * w1.w;
    }
    #pragma unroll
    for (int off = 8; off >= 1; off >>= 1) {
        p0 += __shfl_xor(p0, off, 16);
        p1 += __shfl_xor(p1, off, 16);
    }
    if ((t & 15) == 0) {
        out[(size_t)row * 2 + 0] = p0 + bias[0];
        out[(size_t)row * 2 + 1] = p1 + bias[1];
    }
}

// ---------------------------------------------------------------------------
extern "C" void kernel_launch(void* const* d_in, const int* in_sizes, int n_in,
                              void* d_out, int out_size, void* d_ws, size_t ws_size,
                              hipStream_t stream)
{
    const float* inputs = (const float*)d_in[0];
    const float* h0     = (const float*)d_in[1];
    const float* c0     = (const float*)d_in[2];
    const float* m1w1 = (const float*)d_in[3];  const float* m1b1 = (const float*)d_in[4];
    const float* m1w2 = (const float*)d_in[5];  const float* m1b2 = (const float*)d_in[6];
    const float* m1w3 = (const float*)d_in[7];  const float* m1b3 = (const float*)d_in[8];
    const float* m2w1 = (const float*)d_in[9];  const float* m2b1 = (const float*)d_in[10];
    const float* m2w2 = (const float*)d_in[11]; const float* m2b2 = (const float*)d_in[12];
    const float* m2w3 = (const float*)d_in[13]; const float* m2b3 = (const float*)d_in[14];
    const float* m3w1 = (const float*)d_in[15]; const float* m3b1 = (const float*)d_in[16];
    const float* m3w2 = (const float*)d_in[17]; const float* m3b2 = (const float*)d_in[18];
    const float* m3w3 = (const float*)d_in[19]; const float* m3b3 = (const float*)d_in[20];
    const float* m4w1 = (const float*)d_in[21]; const float* m4b1 = (const float*)d_in[22];
    const float* m4w2 = (const float*)d_in[23]; const float* m4b2 = (const float*)d_in[24];
    const float* m4w3 = (const float*)d_in[25]; const float* m4b3 = (const float*)d_in[26];
    const float* wih  = (const float*)d_in[27]; const float* whh  = (const float*)d_in[28];
    const float* bih  = (const float*)d_in[29]; const float* bhh  = (const float*)d_in[30];
    const float* pw1  = (const float*)d_in[31]; const float* pb1  = (const float*)d_in[32];
    const float* pw2  = (const float*)d_in[33]; const float* pb2  = (const float*)d_in[34];
    const float* pw3  = (const float*)d_in[35]; const float* pb3  = (const float*)d_in[36];

    float* out   = (float*)d_out;
    float* prior = out;                               // [ME,2]
    float* h1    = out + (size_t)ME * 2;              // [ME,H]
    float* c1    = h1 + (size_t)ME * H_;              // [ME,H]

    float* ws = (float*)d_ws;
    float* BA = ws;                                   // [ME,H] big ping
    float* BB = BA + (size_t)ME * H_;                 // [ME,H] big pong
    float* S0 = BB + (size_t)ME * H_;                 // [MV,H]
    float* S1 = S0 + (size_t)MV * H_;
    float* S2 = S1 + (size_t)MV * H_;
    float* S3 = S2 + (size_t)MV * H_;

    const dim3 blk(256);
    const dim3 gV(MV / 64, 4);   // node-row GEMMs, N=256
    const dim3 gE(ME / 64, 4);   // edge-row GEMMs, N=256

    // MLP1: inputs[MV,64] -> S0 -> S1 -> S0 (=X1)
    gemm_k<0><<<gV, blk, 0, stream>>>(inputs, 64, m1w1, 64, m1b1, S0, MV, 256, 64, 1, nullptr, nullptr);
    gemm_k<0><<<gV, blk, 0, stream>>>(S0, 256, m1w2, 256, m1b2, S1, MV, 256, 256, 1, nullptr, nullptr);
    gemm_k<0><<<gV, blk, 0, stream>>>(S1, 256, m1w3, 256, m1b3, S0, MV, 256, 256, 0, nullptr, nullptr);

    // Ys = X1 @ m2w1[:, :256].T ; Yr = X1 @ m2w1[:, 256:].T
    gemm_k<0><<<gV, blk, 0, stream>>>(S0, 256, m2w1,       512, nullptr, S2, MV, 256, 256, 0, nullptr, nullptr);
    gemm_k<0><<<gV, blk, 0, stream>>>(S0, 256, m2w1 + 256, 512, nullptr, S3, MV, 256, 256, 0, nullptr, nullptr);

    // MLP2: L1 gather-add -> BA ; L2 -> BB ; L3 -> BA (=X2 / x_skip)
    edge_l1_k<<<ME, blk, 0, stream>>>(S2, S3, m2b1, BA);
    gemm_k<0><<<gE, blk, 0, stream>>>(BA, 256, m2w2, 256, m2b2, BB, ME, 256, 256, 1, nullptr, nullptr);
    gemm_k<0><<<gE, blk, 0, stream>>>(BB, 256, m2w3, 256, m2b3, BA, ME, 256, 256, 0, nullptr, nullptr);

    // aggregate -> S0 ; MLP3 -> S1 -> S0 -> S1 (=X3)
    agg_k<<<MV * H_ / 256, blk, 0, stream>>>(BA, S0);
    gemm_k<0><<<gV, blk, 0, stream>>>(S0, 256, m3w1, 256, m3b1, S1, MV, 256, 256, 1, nullptr, nullptr);
    gemm_k<0><<<gV, blk, 0, stream>>>(S1, 256, m3w2, 256, m3b2, S0, MV, 256, 256, 1, nullptr, nullptr);
    gemm_k<0><<<gV, blk, 0, stream>>>(S0, 256, m3w3, 256, m3b3, S1, MV, 256, 256, 0, nullptr, nullptr);

    // Zs = X3 @ m4w1[:, :256].T ; Zr = X3 @ m4w1[:, 256:512].T
    gemm_k<0><<<gV, blk, 0, stream>>>(S1, 256, m4w1,       768, nullptr, S2, MV, 256, 256, 0, nullptr, nullptr);
    gemm_k<0><<<gV, blk, 0, stream>>>(S1, 256, m4w1 + 256, 768, nullptr, S3, MV, 256, 256, 0, nullptr, nullptr);

    // MLP4: L1 = relu(X2 @ m4w1[:,512:].T + Zs[send] + Zr[recv] + b) -> BB
    gemm_k<1><<<gE, blk, 0, stream>>>(BA, 256, m4w1 + 512, 768, m4b1, BB, ME, 256, 256, 1, S2, S3);
    gemm_k<0><<<gE, blk, 0, stream>>>(BB, 256, m4w2, 256, m4b2, BA, ME, 256, 256, 1, nullptr, nullptr);
    gemm_k<0><<<gE, blk, 0, stream>>>(BA, 256, m4w3, 256, m4b3, BB, ME, 256, 256, 0, nullptr, nullptr);  // =x4

    // LSTM: h1, c1 straight into d_out
    lstm_k<<<dim3(ME / 64, 8), blk, 0, stream>>>(BB, h0, c0, wih, whh, bih, bhh, h1, c1);

    // prior MLP: h1 -> BA -> BB -> prior[ME,2]
    gemm_k<0><<<gE, blk, 0, stream>>>(h1, 256, pw1, 256, pb1, BA, ME, 256, 256, 1, nullptr, nullptr);
    gemm_k<0><<<gE, blk, 0, stream>>>(BA, 256, pw2, 256, pb2, BB, ME, 256, 256, 1, nullptr, nullptr);
    prior3_k<<<ME / 16, blk, 0, stream>>>(BB, pw3, pb3, prior);
}

// Round 3
// 1331.421 us; speedup vs baseline: 3.1581x; 3.1581x over previous
//
#include <hip/hip_runtime.h>
#include <math.h>

#define B_ 128
#define V_ 32
#define D_ 64
#define H_ 256
#define E_ 992
#define ME (B_*E_)   // 126976
#define MV (B_*V_)   // 4096

typedef __attribute__((ext_vector_type(8))) short bf8v;       // 8 bf16 fragment
typedef __attribute__((ext_vector_type(4))) float f4v;        // MFMA accumulator
typedef __attribute__((ext_vector_type(8))) unsigned short u16x8;

__device__ __forceinline__ unsigned short f2bf(float f) {
    union { float f; unsigned int u; } v; v.f = f;
    unsigned int u = v.u + 0x7FFFu + ((v.u >> 16) & 1u);   // RNE
    return (unsigned short)(u >> 16);
}
__device__ __forceinline__ float bf2f(unsigned short h) {
    union { unsigned int u; float f; } v; v.u = ((unsigned int)h) << 16;
    return v.f;
}
__device__ __forceinline__ float sigf(float x) {
    x = fminf(fmaxf(x, -30.f), 30.f);
    return 1.f / (1.f + __expf(-x));
}
__device__ __forceinline__ float tanhf_fast(float x) {
    x = fminf(fmaxf(x, -15.f), 15.f);
    float e = __expf(2.f * x);
    return (e - 1.f) / (e + 1.f);
}
__device__ __forceinline__ void gl_lds16(const unsigned short* g, unsigned short* l) {
    __builtin_amdgcn_global_load_lds(
        (const __attribute__((address_space(1))) unsigned int*)g,
        (__attribute__((address_space(3))) unsigned int*)l, 16, 0, 0);
}

// ---------------------------------------------------------------------------
// fp32 -> bf16 conversion (contiguous, 4 elems/thread)
// ---------------------------------------------------------------------------
__global__ __launch_bounds__(256)
void f2b_k(const float* __restrict__ s, unsigned short* __restrict__ d, int n4)
{
    const int g = blockIdx.x * 256 + threadIdx.x;
    if (g >= n4) return;
    const float4 v = ((const float4*)s)[g];
    ushort4 o;
    o.x = f2bf(v.x); o.y = f2bf(v.y); o.z = f2bf(v.z); o.w = f2bf(v.w);
    ((ushort4*)d)[g] = o;
}

// strided slice conversion (for m4w1[:, 512:768])
__global__ __launch_bounds__(256)
void f2bs_k(const float* __restrict__ s, unsigned short* __restrict__ d,
            int rows, int cols4, int ld, int off)
{
    const int g = blockIdx.x * 256 + threadIdx.x;
    if (g >= rows * cols4) return;
    const int r = g / cols4, c4 = g - r * cols4;
    const float4 v = *(const float4*)(s + (size_t)r * ld + off + c4 * 4);
    ushort4 o;
    o.x = f2bf(v.x); o.y = f2bf(v.y); o.z = f2bf(v.z); o.w = f2bf(v.w);
    *(ushort4*)(d + (size_t)r * cols4 * 4 + c4 * 4) = o;
}

// ---------------------------------------------------------------------------
// fp32 VALU GEMM (node path only, small).
// out[m,n] = act( sum_k A[m,k]*W[n*ldw+k] + bias[n] )
// ---------------------------------------------------------------------------
__global__ __launch_bounds__(256)
void gemm_k(const float* __restrict__ A, int lda,
            const float* __restrict__ W, int ldw,
            const float* __restrict__ bias,
            float* __restrict__ out,
            int M, int N, int K, int do_relu)
{
    __shared__ float As[32][68];
    __shared__ float Ws[32][68];
    const int m0 = blockIdx.x * 64;
    const int n0 = blockIdx.y * 64;
    const int t  = threadIdx.x;
    const int tx = t & 15, ty = t >> 4;
    const int lm = t >> 3;
    const int lk = (t & 7) * 4;

    float acc[4][4] = {};

    for (int k0 = 0; k0 < K; k0 += 32) {
        #pragma unroll
        for (int h = 0; h < 2; ++h) {
            const int m = m0 + lm + h * 32;
            const float4 v = *(const float4*)(A + (size_t)m * lda + k0 + lk);
            As[lk + 0][lm + h * 32] = v.x;
            As[lk + 1][lm + h * 32] = v.y;
            As[lk + 2][lm + h * 32] = v.z;
            As[lk + 3][lm + h * 32] = v.w;
            const int n = n0 + lm + h * 32;
            const float4 w = *(const float4*)(W + (size_t)n * ldw + k0 + lk);
            Ws[lk + 0][lm + h * 32] = w.x;
            Ws[lk + 1][lm + h * 32] = w.y;
            Ws[lk + 2][lm + h * 32] = w.z;
            Ws[lk + 3][lm + h * 32] = w.w;
        }
        __syncthreads();
        #pragma unroll
        for (int kk = 0; kk < 32; ++kk) {
            float a[4], b[4];
            #pragma unroll
            for (int i = 0; i < 4; ++i) a[i] = As[kk][ty * 4 + i];
            #pragma unroll
            for (int j = 0; j < 4; ++j) b[j] = Ws[kk][tx * 4 + j];
            #pragma unroll
            for (int i = 0; i < 4; ++i)
                #pragma unroll
                for (int j = 0; j < 4; ++j)
                    acc[i][j] = fmaf(a[i], b[j], acc[i][j]);
        }
        __syncthreads();
    }

    #pragma unroll
    for (int i = 0; i < 4; ++i) {
        const int m = m0 + ty * 4 + i;
        const size_t ob = (size_t)m * N;
        #pragma unroll
        for (int j = 0; j < 4; ++j) {
            const int n = n0 + tx * 4 + j;
            float v = acc[i][j];
            if (bias) v += bias[n];
            if (do_relu) v = fmaxf(v, 0.f);
            out[ob + n] = v;
        }
    }
}

// ---------------------------------------------------------------------------
// bf16 MFMA GEMM: out[m,n] = act( sum_k A[m,k]*W[n,k] + bias[n] [+ES+ER] )
// A bf16 [M,lda], W bf16 [256,256] compact, out bf16 [M,256].
// M=ME, N=256, K=256 fixed. 128x128 tile, BK=32, dbuf LDS, global_load_lds.
// m97-verified structure: 4 waves (2x2), wave=64x64, 16 MFMA + 8 ds_read/step.
// ---------------------------------------------------------------------------
template<int EPI, int RELU>
__global__ __launch_bounds__(256)
void gemm_mfma(const unsigned short* __restrict__ A, int lda,
               const unsigned short* __restrict__ W,
               const float* __restrict__ bias,
               unsigned short* __restrict__ out,
               const float* __restrict__ ES, const float* __restrict__ ER)
{
    __shared__ alignas(16) unsigned short As[2][4096];   // [128][32] bf16
    __shared__ alignas(16) unsigned short Bs[2][4096];
    const int t = threadIdx.x;
    const int lane = t & 63, wid = t >> 6;
    const int wr = wid >> 1, wc = wid & 1;
    const int m0 = blockIdx.x * 128, n0 = blockIdx.y * 128;
    const int srow = t >> 2, scol = (t & 3) * 8;

    f4v acc[4][4];
    #pragma unroll
    for (int i = 0; i < 4; ++i)
        #pragma unroll
        for (int j = 0; j < 4; ++j)
            acc[i][j] = (f4v){0.f, 0.f, 0.f, 0.f};

#define STAGE_G(buf, k0) do { \
    gl_lds16(A + (size_t)(m0 + srow) * lda + (k0) + scol,      &As[buf][t * 8]); \
    gl_lds16(A + (size_t)(m0 + 64 + srow) * lda + (k0) + scol, &As[buf][2048 + t * 8]); \
    gl_lds16(W + (size_t)(n0 + srow) * 256 + (k0) + scol,      &Bs[buf][t * 8]); \
    gl_lds16(W + (size_t)(n0 + 64 + srow) * 256 + (k0) + scol, &Bs[buf][2048 + t * 8]); \
} while (0)

    STAGE_G(0, 0);
    __syncthreads();
    int cur = 0;
    #pragma unroll
    for (int s = 0; s < 8; ++s) {
        if (s < 7) STAGE_G(cur ^ 1, (s + 1) * 32);
        const unsigned short* Ab = As[cur];
        const unsigned short* Bb = Bs[cur];
        const int kof = (lane >> 4) * 8;
        const int rA = wr * 64 + (lane & 15);
        const int rB = wc * 64 + (lane & 15);
        bf8v af[4], bv[4];
        #pragma unroll
        for (int f = 0; f < 4; ++f) af[f] = *(const bf8v*)&Ab[(rA + f * 16) * 32 + kof];
        #pragma unroll
        for (int f = 0; f < 4; ++f) bv[f] = *(const bf8v*)&Bb[(rB + f * 16) * 32 + kof];
        #pragma unroll
        for (int i = 0; i < 4; ++i)
            #pragma unroll
            for (int j = 0; j < 4; ++j)
                acc[i][j] = __builtin_amdgcn_mfma_f32_16x16x32_bf16(af[i], bv[j], acc[i][j], 0, 0, 0);
        __syncthreads();
        cur ^= 1;
    }
#undef STAGE_G

    #pragma unroll
    for (int i = 0; i < 4; ++i) {
        #pragma unroll
        for (int r = 0; r < 4; ++r) {
            const int m = m0 + wr * 64 + i * 16 + (lane >> 4) * 4 + r;
            size_t bs = 0, br = 0;
            if (EPI) {
                const int bb = m / E_;
                const int e  = m - bb * E_;
                const int sS = e / 31;
                const int jj = e - sS * 31;
                const int rr = jj + (jj >= sS ? 1 : 0);
                bs = ((size_t)bb * V_ + sS) * H_;
                br = ((size_t)bb * V_ + rr) * H_;
            }
            const size_t ob = (size_t)m * 256;
            #pragma unroll
            for (int j = 0; j < 4; ++j) {
                const int n = n0 + wc * 64 + j * 16 + (lane & 15);
                float v = acc[i][j][r] + bias[n];
                if (EPI) v += ES[bs + n] + ER[br + n];
                if (RELU) v = fmaxf(v, 0.f);
                out[ob + n] = f2bf(v);
            }
        }
    }
}

// ---------------------------------------------------------------------------
// Fused MFMA LSTM. gates = x4@wih.T + h0@whh.T (+biases), cell update inline.
// Block: 128 rows x (32 j x 4 gates). Wave b-fragments = same 16 j from each
// of the 4 gates -> each lane holds i/f/g/o for its (row, j). K=512 (x4|h0).
// ---------------------------------------------------------------------------
__global__ __launch_bounds__(256)
void lstm_mfma(const unsigned short* __restrict__ x4b, const unsigned short* __restrict__ h0b,
               const float* __restrict__ c0,
               const unsigned short* __restrict__ wihb, const unsigned short* __restrict__ whhb,
               const float* __restrict__ bih, const float* __restrict__ bhh,
               float* __restrict__ h1, float* __restrict__ c1,
               unsigned short* __restrict__ h1b)
{
    __shared__ alignas(16) unsigned short As[2][4096];
    __shared__ alignas(16) unsigned short Bs[2][4096];   // row rl = gate*32+jj
    const int t = threadIdx.x;
    const int lane = t & 63, wid = t >> 6;
    const int wr = wid >> 1, wc = wid & 1;
    const int m0 = blockIdx.x * 128;
    const int jb = blockIdx.y * 32;
    const int srow = t >> 2, scol = (t & 3) * 8;
    const int rl0 = srow, rl1 = srow + 64;
    const size_t wrow0 = (size_t)((rl0 >> 5) * 256 + jb + (rl0 & 31)) * 256;
    const size_t wrow1 = (size_t)((rl1 >> 5) * 256 + jb + (rl1 & 31)) * 256;

    f4v acc[4][4];
    #pragma unroll
    for (int i = 0; i < 4; ++i)
        #pragma unroll
        for (int j = 0; j < 4; ++j)
            acc[i][j] = (f4v){0.f, 0.f, 0.f, 0.f};

#define STAGE_L(buf, s) do { \
    const int k0_ = (s) * 32; \
    const unsigned short* Ap_ = (k0_ < 256) ? x4b : h0b; \
    const unsigned short* Wp_ = (k0_ < 256) ? wihb : whhb; \
    const int kk_ = k0_ & 255; \
    gl_lds16(Ap_ + (size_t)(m0 + srow) * 256 + kk_ + scol,      &As[buf][t * 8]); \
    gl_lds16(Ap_ + (size_t)(m0 + 64 + srow) * 256 + kk_ + scol, &As[buf][2048 + t * 8]); \
    gl_lds16(Wp_ + wrow0 + kk_ + scol, &Bs[buf][t * 8]); \
    gl_lds16(Wp_ + wrow1 + kk_ + scol, &Bs[buf][2048 + t * 8]); \
} while (0)

    STAGE_L(0, 0);
    __syncthreads();
    int cur = 0;
    #pragma unroll
    for (int s = 0; s < 16; ++s) {
        if (s < 15) STAGE_L(cur ^ 1, s + 1);
        const unsigned short* Ab = As[cur];
        const unsigned short* Bb = Bs[cur];
        const int kof = (lane >> 4) * 8;
        const int rA = wr * 64 + (lane & 15);
        bf8v af[4], bg[4];
        #pragma unroll
        for (int f = 0; f < 4; ++f) af[f] = *(const bf8v*)&Ab[(rA + f * 16) * 32 + kof];
        #pragma unroll
        for (int g = 0; g < 4; ++g) bg[g] = *(const bf8v*)&Bb[(g * 32 + wc * 16 + (lane & 15)) * 32 + kof];
        #pragma unroll
        for (int i = 0; i < 4; ++i)
            #pragma unroll
            for (int g = 0; g < 4; ++g)
                acc[i][g] = __builtin_amdgcn_mfma_f32_16x16x32_bf16(af[i], bg[g], acc[i][g], 0, 0, 0);
        __syncthreads();
        cur ^= 1;
    }
#undef STAGE_L

    const int j = jb + wc * 16 + (lane & 15);
    const float bi0 = bih[j] + bhh[j];
    const float bi1 = bih[256 + j] + bhh[256 + j];
    const float bi2 = bih[512 + j] + bhh[512 + j];
    const float bi3 = bih[768 + j] + bhh[768 + j];
    #pragma unroll
    for (int i = 0; i < 4; ++i) {
        #pragma unroll
        for (int r = 0; r < 4; ++r) {
            const int row = m0 + wr * 64 + i * 16 + (lane >> 4) * 4 + r;
            const size_t o = (size_t)row * 256 + j;
            const float gi = acc[i][0][r] + bi0;
            const float gf = acc[i][1][r] + bi1;
            const float gg = acc[i][2][r] + bi2;
            const float go = acc[i][3][r] + bi3;
            const float cn = sigf(gf) * c0[o] + sigf(gi) * tanhf_fast(gg);
            const float hn = sigf(go) * tanhf_fast(cn);
            c1[o] = cn;
            h1[o] = hn;
            h1b[o] = f2bf(hn);
        }
    }
}

// ---------------------------------------------------------------------------
// MLP2 layer 1: out[b,e,n] = relu(Ys[b,send,n]+Yr[b,recv,n]+bias[n]) -> bf16
// ---------------------------------------------------------------------------
__global__ __launch_bounds__(256)
void edge_l1_k(const float* __restrict__ Ys, const float* __restrict__ Yr,
               const float* __restrict__ bias, unsigned short* __restrict__ out)
{
    const int g = blockIdx.x * 256 + threadIdx.x;   // over ME*64 (4 elems each)
    const int n4  = (g & 63) * 4;
    const int row = g >> 6;
    const int b = row / E_;
    const int e = row - b * E_;
    const int s = e / 31;
    const int jj = e - s * 31;
    const int r = jj + (jj >= s ? 1 : 0);
    const float4 ys = *(const float4*)(Ys + ((size_t)b * V_ + s) * H_ + n4);
    const float4 yr = *(const float4*)(Yr + ((size_t)b * V_ + r) * H_ + n4);
    const float4 bv = *(const float4*)(bias + n4);
    ushort4 o;
    o.x = f2bf(fmaxf(ys.x + yr.x + bv.x, 0.f));
    o.y = f2bf(fmaxf(ys.y + yr.y + bv.y, 0.f));
    o.z = f2bf(fmaxf(ys.z + yr.z + bv.z, 0.f));
    o.w = f2bf(fmaxf(ys.w + yr.w + bv.w, 0.f));
    *(ushort4*)(out + (size_t)row * 256 + n4) = o;
}

// ---------------------------------------------------------------------------
// edge->node aggregation (bf16 in, fp32 out)
// ---------------------------------------------------------------------------
__global__ __launch_bounds__(256)
void agg_k(const unsigned short* __restrict__ X2, float* __restrict__ outv)
{
    const int g = blockIdx.x * 256 + threadIdx.x;   // over MV*H
    const int h = g & 255;
    const int v = (g >> 8) & 31;
    const int b = g >> 13;
    float s = 0.f;
    #pragma unroll
    for (int snd = 0; snd < 32; ++snd) {
        if (snd == v) continue;
        const int e = snd * 31 + v - (snd < v ? 1 : 0);
        s += bf2f(X2[((size_t)b * E_ + e) * H_ + h]);
    }
    outv[g] = s * (1.f / 31.f);
}

// ---------------------------------------------------------------------------
// Prior layer 3 (bf16 in): out[row,0:2] = H @ pw3.T + pb3
// ---------------------------------------------------------------------------
__global__ __launch_bounds__(256)
void prior3_k(const unsigned short* __restrict__ Hin, const float* __restrict__ w,
              const float* __restrict__ bias, float* __restrict__ out)
{
    const int t   = threadIdx.x;
    const int row = blockIdx.x * 16 + (t >> 4);
    const int kb  = (t & 15) * 16;
    const unsigned short* a = Hin + (size_t)row * 256 + kb;
    const u16x8 a0 = *(const u16x8*)a;
    const u16x8 a1 = *(const u16x8*)(a + 8);
    float p0 = 0.f, p1 = 0.f;
    #pragma unroll
    for (int i = 0; i < 8; ++i) {
        const float x0 = bf2f(a0[i]), x1 = bf2f(a1[i]);
        p0 += x0 * w[kb + i] + x1 * w[kb + 8 + i];
        p1 += x0 * w[256 + kb + i] + x1 * w[256 + kb + 8 + i];
    }
    #pragma unroll
    for (int off = 8; off >= 1; off >>= 1) {
        p0 += __shfl_xor(p0, off, 16);
        p1 += __shfl_xor(p1, off, 16);
    }
    if ((t & 15) == 0) {
        out[(size_t)row * 2 + 0] = p0 + bias[0];
        out[(size_t)row * 2 + 1] = p1 + bias[1];
    }
}

// ---------------------------------------------------------------------------
extern "C" void kernel_launch(void* const* d_in, const int* in_sizes, int n_in,
                              void* d_out, int out_size, void* d_ws, size_t ws_size,
                              hipStream_t stream)
{
    const float* inputs = (const float*)d_in[0];
    const float* h0     = (const float*)d_in[1];
    const float* c0     = (const float*)d_in[2];
    const float* m1w1 = (const float*)d_in[3];  const float* m1b1 = (const float*)d_in[4];
    const float* m1w2 = (const float*)d_in[5];  const float* m1b2 = (const float*)d_in[6];
    const float* m1w3 = (const float*)d_in[7];  const float* m1b3 = (const float*)d_in[8];
    const float* m2w1 = (const float*)d_in[9];  const float* m2b1 = (const float*)d_in[10];
    const float* m2w2 = (const float*)d_in[11]; const float* m2b2 = (const float*)d_in[12];
    const float* m2w3 = (const float*)d_in[13]; const float* m2b3 = (const float*)d_in[14];
    const float* m3w1 = (const float*)d_in[15]; const float* m3b1 = (const float*)d_in[16];
    const float* m3w2 = (const float*)d_in[17]; const float* m3b2 = (const float*)d_in[18];
    const float* m3w3 = (const float*)d_in[19]; const float* m3b3 = (const float*)d_in[20];
    const float* m4w1 = (const float*)d_in[21]; const float* m4b1 = (const float*)d_in[22];
    const float* m4w2 = (const float*)d_in[23]; const float* m4b2 = (const float*)d_in[24];
    const float* m4w3 = (const float*)d_in[25]; const float* m4b3 = (const float*)d_in[26];
    const float* wih  = (const float*)d_in[27]; const float* whh  = (const float*)d_in[28];
    const float* bih  = (const float*)d_in[29]; const float* bhh  = (const float*)d_in[30];
    const float* pw1  = (const float*)d_in[31]; const float* pb1  = (const float*)d_in[32];
    const float* pw2  = (const float*)d_in[33]; const float* pb2  = (const float*)d_in[34];
    const float* pw3  = (const float*)d_in[35]; const float* pb3  = (const float*)d_in[36];

    float* out   = (float*)d_out;
    float* prior = out;
    float* h1    = out + (size_t)ME * 2;
    float* c1    = h1 + (size_t)ME * H_;

    // workspace layout
    float* S0 = (float*)d_ws;                 // 4 node fp32 buffers [MV,256]
    float* S1 = S0 + (size_t)MV * H_;
    float* S2 = S1 + (size_t)MV * H_;
    float* S3 = S2 + (size_t)MV * H_;
    unsigned short* EA = (unsigned short*)(S3 + (size_t)MV * H_);  // 3 edge bf16 [ME,256]
    unsigned short* EB = EA + (size_t)ME * H_;
    unsigned short* EC = EB + (size_t)ME * H_;
    unsigned short* cw22 = EC + (size_t)ME * H_;   // bf16 weights
    unsigned short* cw23 = cw22 + 65536;
    unsigned short* cw41 = cw23 + 65536;           // m4w1[:,512:768] compacted
    unsigned short* cw42 = cw41 + 65536;
    unsigned short* cw43 = cw42 + 65536;
    unsigned short* cpw1 = cw43 + 65536;
    unsigned short* cpw2 = cpw1 + 65536;
    unsigned short* cwih = cpw2 + 65536;
    unsigned short* cwhh = cwih + 262144;

    const dim3 blk(256);
    const dim3 gV(MV / 64, 4);      // node fp32 GEMMs
    const dim3 gM(ME / 128, 2);     // edge MFMA GEMMs

    // weight + h0 conversions
    f2b_k<<<64, blk, 0, stream>>>(m2w2, cw22, 16384);
    f2b_k<<<64, blk, 0, stream>>>(m2w3, cw23, 16384);
    f2bs_k<<<64, blk, 0, stream>>>(m4w1, cw41, 256, 64, 768, 512);
    f2b_k<<<64, blk, 0, stream>>>(m4w2, cw42, 16384);
    f2b_k<<<64, blk, 0, stream>>>(m4w3, cw43, 16384);
    f2b_k<<<64, blk, 0, stream>>>(pw1, cpw1, 16384);
    f2b_k<<<64, blk, 0, stream>>>(pw2, cpw2, 16384);
    f2b_k<<<256, blk, 0, stream>>>(wih, cwih, 65536);
    f2b_k<<<256, blk, 0, stream>>>(whh, cwhh, 65536);
    f2b_k<<<ME * H_ / 1024, blk, 0, stream>>>(h0, EC, ME * H_ / 4);   // h0 -> bf16

    // MLP1 (node, fp32): inputs -> S0 -> S1 -> S0 (=X1)
    gemm_k<<<gV, blk, 0, stream>>>(inputs, 64, m1w1, 64, m1b1, S0, MV, 256, 64, 1);
    gemm_k<<<gV, blk, 0, stream>>>(S0, 256, m1w2, 256, m1b2, S1, MV, 256, 256, 1);
    gemm_k<<<gV, blk, 0, stream>>>(S1, 256, m1w3, 256, m1b3, S0, MV, 256, 256, 0);

    // Ys / Yr projections (node, fp32)
    gemm_k<<<gV, blk, 0, stream>>>(S0, 256, m2w1,       512, nullptr, S2, MV, 256, 256, 0);
    gemm_k<<<gV, blk, 0, stream>>>(S0, 256, m2w1 + 256, 512, nullptr, S3, MV, 256, 256, 0);

    // MLP2: L1 gather -> EA(bf16); L2 -> EB; L3 -> EA (=X2 / x_skip)
    edge_l1_k<<<ME * 64 / 256, blk, 0, stream>>>(S2, S3, m2b1, EA);
    gemm_mfma<0, 1><<<gM, blk, 0, stream>>>(EA, 256, cw22, m2b2, EB, nullptr, nullptr);
    gemm_mfma<0, 0><<<gM, blk, 0, stream>>>(EB, 256, cw23, m2b3, EA, nullptr, nullptr);

    // aggregate -> S0 ; MLP3 (node, fp32) -> S1 (=X3)
    agg_k<<<MV * H_ / 256, blk, 0, stream>>>(EA, S0);
    gemm_k<<<gV, blk, 0, stream>>>(S0, 256, m3w1, 256, m3b1, S1, MV, 256, 256, 1);
    gemm_k<<<gV, blk, 0, stream>>>(S1, 256, m3w2, 256, m3b2, S0, MV, 256, 256, 1);
    gemm_k<<<gV, blk, 0, stream>>>(S0, 256, m3w3, 256, m3b3, S1, MV, 256, 256, 0);

    // Zs / Zr projections (node, fp32)
    gemm_k<<<gV, blk, 0, stream>>>(S1, 256, m4w1,       768, nullptr, S2, MV, 256, 256, 0);
    gemm_k<<<gV, blk, 0, stream>>>(S1, 256, m4w1 + 256, 768, nullptr, S3, MV, 256, 256, 0);

    // MLP4: L1 (MFMA + gather epilogue) -> EB; L2 -> EA; L3 -> EB (=x4)
    gemm_mfma<1, 1><<<gM, blk, 0, stream>>>(EA, 256, cw41, m4b1, EB, S2, S3);
    gemm_mfma<0, 1><<<gM, blk, 0, stream>>>(EB, 256, cw42, m4b2, EA, nullptr, nullptr);
    gemm_mfma<0, 0><<<gM, blk, 0, stream>>>(EA, 256, cw43, m4b3, EB, nullptr, nullptr);

    // fused LSTM (MFMA): h1,c1 -> d_out, h1 bf16 -> EA
    lstm_mfma<<<dim3(ME / 128, 8), blk, 0, stream>>>(EB, EC, c0, cwih, cwhh, bih, bhh, h1, c1, EA);

    // prior MLP: EA -> EB -> EC -> prior
    gemm_mfma<0, 1><<<gM, blk, 0, stream>>>(EA, 256, cpw1, pb1, EB, nullptr, nullptr);
    gemm_mfma<0, 1><<<gM, blk, 0, stream>>>(EB, 256, cpw2, pb2, EC, nullptr, nullptr);
    prior3_k<<<ME / 16, blk, 0, stream>>>(EC, pw3, pb3, prior);
}